// Round 2
// baseline (212.864 us; speedup 1.0000x reference)
//
#include <hip/hip_runtime.h>

// Problem constants (from setup_inputs)
#define BB   16      // batches
#define NA   2048    // anchor rows per batch
#define NP   2048    // positive rows per batch
#define DD   512     // feature dim
#define KSEL 32      // selected indices per batch
#define TR   256     // tile rows per match block
#define NT   (NP/TR) // 8 tiles per (batch, matrix)
#define DC   32      // d-chunk (floats) staged per iteration
#define NCH  (DD/DC) // 16 chunks

// Workspace layout (in floats)
#define QT_OFF   0
#define QT_SZ    (BB*DD*KSEL)        // 262144 floats: Qt[b][d][k], normalized queries, transposed
#define PMAX_OFF (QT_OFF + QT_SZ)
#define PRED_SZ  (BB*2*NT*KSEL)      // 8192 per array
#define PIDX_OFF (PMAX_OFF + PRED_SZ)

__device__ __forceinline__ void gload_lds16(const void* g, void* l) {
  __builtin_amdgcn_global_load_lds(
      (const __attribute__((address_space(1))) unsigned int*)g,
      (__attribute__((address_space(3))) unsigned int*)l,
      16, 0, 0);
}

// ---------------------------------------------------------------------------
// Kernel A: gather + normalize selected anchor rows.
//   - idx_a rows -> A_s output (coalesced)
//   - idx_p rows -> Qt workspace, transposed [b][d][k] (scattered 4B writes,
//     only 1MB total; makes kernel B's LDS staging fully coalesced)
// ---------------------------------------------------------------------------
__global__ __launch_bounds__(256) void prep_kernel(
    const float* __restrict__ anchor, const int* __restrict__ idx_a,
    const int* __restrict__ idx_p, float* __restrict__ outA,
    float* __restrict__ qt_ws) {
  const int blk = blockIdx.x;          // b*32 + k
  const int b = blk >> 5, k = blk & 31;
  const int t = threadIdx.x;
  const int ia = idx_a[blk];
  const int ip = idx_p[blk];
  const float* rowA = anchor + ((size_t)(b*NA + ia))*DD;
  const float* rowP = anchor + ((size_t)(b*NA + ip))*DD;

  float2 a2 = *(const float2*)(rowA + 2*t);
  float2 p2 = *(const float2*)(rowP + 2*t);
  float sa = a2.x*a2.x + a2.y*a2.y;
  float sp = p2.x*p2.x + p2.y*p2.y;
  #pragma unroll
  for (int o = 1; o < 64; o <<= 1) {
    sa += __shfl_xor(sa, o, 64);
    sp += __shfl_xor(sp, o, 64);
  }
  __shared__ float lb[8];
  const int w = t >> 6, l = t & 63;
  if (l == 0) { lb[w] = sa; lb[4+w] = sp; }
  __syncthreads();
  sa = lb[0]+lb[1]+lb[2]+lb[3];
  sp = lb[4]+lb[5]+lb[6]+lb[7];
  const float ra = 1.f / fmaxf(sqrtf(sa), 1e-12f);
  const float rp = 1.f / fmaxf(sqrtf(sp), 1e-12f);

  float2 o2; o2.x = a2.x*ra; o2.y = a2.y*ra;
  *(float2*)(outA + (size_t)blk*DD + 2*t) = o2;

  const int d = 2*t;
  qt_ws[((size_t)b*DD + d  )*KSEL + k] = p2.x*rp;
  qt_ws[((size_t)b*DD + d+1)*KSEL + k] = p2.y*rp;
}

// ---------------------------------------------------------------------------
// Kernel B: per (tile of 256 rows, matrix, batch) compute 32 cosine sims per
// row (p-norms on the fly) and reduce to per-tile (max, argmax) per query.
// LDS: Qt[512][32] (64KB) + double-buffered P chunk [256][32] (2x32KB) = 128KiB.
// Staging via global_load_lds with XOR-swizzled global source so the linear
// LDS destination reads back conflict-free (2-way, which is free per m136).
// ---------------------------------------------------------------------------
__global__ __launch_bounds__(256) void match_kernel(
    const float* __restrict__ p1, const float* __restrict__ p2,
    const float* __restrict__ qt_ws, float* __restrict__ pmax_ws,
    int* __restrict__ pidx_ws) {
  __shared__ float Qt[DD*KSEL];      // [d][q] 64KB
  __shared__ float Ps[2][TR*DC];     // 2 x 32KB

  const int tile = blockIdx.x, mat = blockIdx.y, b = blockIdx.z;
  const float* __restrict__ P =
      (mat ? p2 : p1) + (size_t)b*NP*DD + (size_t)tile*TR*DD;
  const int t = threadIdx.x;
  const int w = t >> 6, l = t & 63;
  const int qg = t & 3;      // 4 query groups of 8
  const int rg = t >> 2;     // 64 row groups of 4

  // Stage Qt (coalesced 64KB copy; qt_ws is already transposed+normalized)
  {
    const float* src = qt_ws + (size_t)b*DD*KSEL;
    #pragma unroll
    for (int i = 0; i < 16; ++i) {
      const int idx4 = i*256 + t;
      *(float4*)&Qt[idx4*4] = *(const float4*)&src[idx4*4];
    }
  }

  // Stage chunk 0 (async, direct to LDS). Per wave: 8 x 1KB instructions.
  // LDS float idx = w*2048 + j*256 + 4l  ->  row r = w*64+j*8+l/8, slot l&7.
  // LDS[r][s] = G[r][s ^ ((r>>2)&7)]  (XOR swizzle, involution).
  {
    float* buf = &Ps[0][0];
    #pragma unroll
    for (int j = 0; j < 8; ++j) {
      const int r = w*64 + j*8 + (l >> 3);
      const int src_dc = (l & 7) ^ ((r >> 2) & 7);
      const float* g = P + (size_t)r*DD + 0*DC + src_dc*4;
      gload_lds16(g, buf + w*2048 + j*256);
    }
  }
  asm volatile("s_waitcnt vmcnt(0)" ::: "memory");
  __syncthreads();

  float acc[8][4];
  float ssq[4];
  #pragma unroll
  for (int jj = 0; jj < 8; ++jj)
    #pragma unroll
    for (int i = 0; i < 4; ++i) acc[jj][i] = 0.f;
  #pragma unroll
  for (int i = 0; i < 4; ++i) ssq[i] = 0.f;

  for (int c = 0; c < NCH; ++c) {
    const int cur = c & 1;
    // Prefetch next chunk into the other buffer
    if (c + 1 < NCH) {
      float* buf = &Ps[cur ^ 1][0];
      #pragma unroll
      for (int j = 0; j < 8; ++j) {
        const int r = w*64 + j*8 + (l >> 3);
        const int src_dc = (l & 7) ^ ((r >> 2) & 7);
        const float* g = P + (size_t)r*DD + (size_t)(c+1)*DC + src_dc*4;
        gload_lds16(g, buf + w*2048 + j*256);
      }
    }
    // Compute on current chunk
    const float* __restrict__ pb = &Ps[cur][0];
    #pragma unroll
    for (int dc4 = 0; dc4 < 8; ++dc4) {
      float pr[4][4];
      #pragma unroll
      for (int i = 0; i < 4; ++i) {
        const int r = rg*4 + i;
        const int pc = dc4 ^ (rg & 7);
        const float4 v = *(const float4*)&pb[r*DC + pc*4];
        pr[i][0] = v.x; pr[i][1] = v.y; pr[i][2] = v.z; pr[i][3] = v.w;
      }
      #pragma unroll
      for (int kk = 0; kk < 4; ++kk) {
        const int dk = c*DC + dc4*4 + kk;
        const float4 q0 = *(const float4*)&Qt[dk*KSEL + qg*8];
        const float4 q1 = *(const float4*)&Qt[dk*KSEL + qg*8 + 4];
        #pragma unroll
        for (int i = 0; i < 4; ++i) {
          const float p = pr[i][kk];
          acc[0][i] += q0.x*p; acc[1][i] += q0.y*p;
          acc[2][i] += q0.z*p; acc[3][i] += q0.w*p;
          acc[4][i] += q1.x*p; acc[5][i] += q1.y*p;
          acc[6][i] += q1.z*p; acc[7][i] += q1.w*p;
          ssq[i] += p*p;
        }
      }
    }
    asm volatile("s_waitcnt vmcnt(0)" ::: "memory");
    __syncthreads();
  }

  // Epilogue: sims = acc * rinv_p; two-level (max, argmax) reduce with
  // first-occurrence tie semantics (ascending row order at every level).
  float rinvp[4];
  #pragma unroll
  for (int i = 0; i < 4; ++i)
    rinvp[i] = 1.f / fmaxf(sqrtf(ssq[i]), 1e-12f);

  float* redv  = &Ps[0][0];                 // [64][32]
  int*   redi  = (int*)&Ps[0][2048];        // [64][32]
  float* red2v = &Ps[0][4096];              // [8][32]
  int*   red2i = (int*)&Ps[0][4096 + 256];  // [8][32]

  #pragma unroll
  for (int jj = 0; jj < 8; ++jj) {
    const int q = qg*8 + jj;
    float best = -1e30f; int bi = 0;
    #pragma unroll
    for (int i = 0; i < 4; ++i) {
      const float s = acc[jj][i] * rinvp[i];
      if (s > best) { best = s; bi = rg*4 + i; }
    }
    redv[rg*32 + q] = best;
    redi[rg*32 + q] = bi;
  }
  __syncthreads();
  {
    const int g = t >> 5, q = t & 31;
    float best = -1e30f; int bi = 0;
    for (int rr = g*8; rr < g*8 + 8; ++rr) {
      const float v = redv[rr*32 + q];
      if (v > best) { best = v; bi = redi[rr*32 + q]; }
    }
    red2v[g*32 + q] = best;
    red2i[g*32 + q] = bi;
  }
  __syncthreads();
  if (t < 32) {
    const int q = t;
    float best = -1e30f; int bi = 0;
    for (int g = 0; g < 8; ++g) {
      const float v = red2v[g*32 + q];
      if (v > best) { best = v; bi = red2i[g*32 + q]; }
    }
    const int o = ((b*2 + mat)*NT + tile)*KSEL + q;
    pmax_ws[o] = best;
    pidx_ws[o] = tile*TR + bi;
  }
}

// ---------------------------------------------------------------------------
// Kernel C: per (b,k) reduce tile partials, gather+normalize matched rows,
// fuse with weights, renormalize, write P_s.
// ---------------------------------------------------------------------------
__global__ __launch_bounds__(256) void fuse_kernel(
    const float* __restrict__ p1, const float* __restrict__ p2,
    const float* __restrict__ pmax_ws, const int* __restrict__ pidx_ws,
    float* __restrict__ outP) {
  const int blk = blockIdx.x;          // b*32 + k
  const int b = blk >> 5, k = blk & 31;
  const int t = threadIdx.x;

  float w1 = -1e30f, w2 = -1e30f; int i1 = 0, i2 = 0;
  for (int tl = 0; tl < NT; ++tl) {
    const int o1 = ((b*2 + 0)*NT + tl)*KSEL + k;
    const float v = pmax_ws[o1];
    if (v > w1) { w1 = v; i1 = pidx_ws[o1]; }
    const int o2 = ((b*2 + 1)*NT + tl)*KSEL + k;
    const float u = pmax_ws[o2];
    if (u > w2) { w2 = u; i2 = pidx_ws[o2]; }
  }

  const float* r1 = p1 + ((size_t)b*NP + i1)*DD;
  const float* r2 = p2 + ((size_t)b*NP + i2)*DD;
  float2 a  = *(const float2*)(r1 + 2*t);
  float2 c2 = *(const float2*)(r2 + 2*t);
  float s1 = a.x*a.x + a.y*a.y;
  float s2 = c2.x*c2.x + c2.y*c2.y;
  #pragma unroll
  for (int o = 1; o < 64; o <<= 1) {
    s1 += __shfl_xor(s1, o, 64);
    s2 += __shfl_xor(s2, o, 64);
  }
  __shared__ float lb[12];
  const int w = t >> 6, l = t & 63;
  if (l == 0) { lb[w] = s1; lb[4+w] = s2; }
  __syncthreads();
  s1 = lb[0]+lb[1]+lb[2]+lb[3];
  s2 = lb[4]+lb[5]+lb[6]+lb[7];
  const float rn1 = 1.f / fmaxf(sqrtf(s1), 1e-12f);
  const float rn2 = 1.f / fmaxf(sqrtf(s2), 1e-12f);

  const float invd = 1.f / (w1 + w2 + 1e-6f);
  const float fx = (w1*(a.x*rn1)  + w2*(c2.x*rn2)) * invd;
  const float fy = (w1*(a.y*rn1)  + w2*(c2.y*rn2)) * invd;

  float sf = fx*fx + fy*fy;
  #pragma unroll
  for (int o = 1; o < 64; o <<= 1) sf += __shfl_xor(sf, o, 64);
  if (l == 0) lb[8+w] = sf;
  __syncthreads();
  sf = lb[8]+lb[9]+lb[10]+lb[11];
  const float rf = 1.f / fmaxf(sqrtf(sf), 1e-12f);

  float2 o2; o2.x = fx*rf; o2.y = fy*rf;
  *(float2*)(outP + (size_t)blk*DD + 2*t) = o2;
}

extern "C" void kernel_launch(void* const* d_in, const int* in_sizes, int n_in,
                              void* d_out, int out_size, void* d_ws, size_t ws_size,
                              hipStream_t stream) {
  (void)in_sizes; (void)n_in; (void)out_size; (void)ws_size;
  const float* anchor = (const float*)d_in[0];
  const float* p1     = (const float*)d_in[1];
  const float* p2     = (const float*)d_in[2];
  const int*   idx_a  = (const int*)d_in[3];
  const int*   idx_p  = (const int*)d_in[4];

  float* out  = (float*)d_out;
  float* outA = out;                       // (B,K,D)
  float* outP = out + (size_t)BB*KSEL*DD;  // (B,K,D)

  float* ws   = (float*)d_ws;
  float* qt   = ws + QT_OFF;
  float* pmax = ws + PMAX_OFF;
  int*   pidx = (int*)(ws + PIDX_OFF);

  hipLaunchKernelGGL(prep_kernel, dim3(BB*KSEL), dim3(256), 0, stream,
                     anchor, idx_a, idx_p, outA, qt);
  hipLaunchKernelGGL(match_kernel, dim3(NT, 2, BB), dim3(256), 0, stream,
                     p1, p2, qt, pmax, pidx);
  hipLaunchKernelGGL(fuse_kernel, dim3(BB*KSEL), dim3(256), 0, stream,
                     p1, p2, pmax, pidx, outP);
}